// Round 4
// baseline (123.742 us; speedup 1.0000x reference)
//
#include <hip/hip_runtime.h>
#include <math.h>

#define KTR 96
#define DIM 256
#define PB  40
#define CH  8
#define MDIM 3840
#define ROWH 640            // f16 per padded global row: 16 chunks x (32+8pad)
#define BM 160              // test rows (l,j): 4 complete groups
#define BNS 128             // enroll cols staged (16-mult for MFMA)
#define BNV 120             // enroll cols valid: 3 complete groups
#define LDA 40              // f16 per LDS row (32 data + 8 pad = 80 B, conflict-free-ish)
#define SZA (BM * LDA * 2)  // bytes per A buffer (12800)
#define SZB (BNS * LDA * 2) // bytes per B buffer (10240)
#define NTAB 2113           // gate table nodes, h = 2^-10, x = (i-1056)/1024

typedef _Float16 v8h __attribute__((ext_vector_type(8)));
typedef float    v4f __attribute__((ext_vector_type(4)));

#define CP16(g, l) __builtin_amdgcn_global_load_lds(                  \
    (const __attribute__((address_space(1))) void*)(g),               \
    (__attribute__((address_space(3))) void*)(l), 16, 0, 0)

__device__ __forceinline__ float gate_ref(float x, const float* w, const float* b, const float* v) {
    float g = 0.f;
    #pragma unroll
    for (int c = 0; c < CH; ++c) g = fmaf(v[c], tanhf(fmaf(w[c], x, b[c])), g);
    return g;
}

// ---------------- Kernel 1: L2-normalize + f16 hi/lo split into padded rows + gate table ----------------
__global__ __launch_bounds__(256) void k_norm(const float* __restrict__ enroll,
                                              const float* __restrict__ test,
                                              const float* __restrict__ fc1_w,
                                              const float* __restrict__ fc1_b,
                                              const float* __restrict__ fc2_w,
                                              _Float16* __restrict__ XT,
                                              _Float16* __restrict__ XE,
                                              float2* __restrict__ gtabG) {
    int b = blockIdx.x, tid = threadIdx.x;

    if (b >= 2 * KTR) {                        // 9 table-builder blocks
        int i = (b - 2 * KTR) * 256 + tid;
        if (i < NTAB) {
            float w[CH], bb[CH], vv[CH];
            #pragma unroll
            for (int c = 0; c < CH; ++c) { w[c] = fc1_w[c]; bb[c] = fc1_b[c]; vv[c] = fc2_w[c]; }
            float x0 = (float)(i - 1056) * 0.0009765625f;
            float g0 = gate_ref(x0, w, bb, vv);
            float g1 = gate_ref(x0 + 0.0009765625f, w, bb, vv);
            gtabG[i] = make_float2(g0, g1 - g0);
        }
        return;
    }

    bool isE = (b < KTR);
    int k = isE ? b : b - KTR;
    const float* src = (isE ? enroll : test) + (size_t)k * DIM * PB;

    __shared__ float S[DIM * 41];
    __shared__ float part[6 * PB];
    __shared__ float rn[PB];

    for (int i = tid; i < DIM * PB / 4; i += 256) {
        float4 v = ((const float4*)src)[i];
        int d = i / 10, c = i - d * 10;
        float* p = &S[d * 41 + c * 4];
        p[0] = v.x; p[1] = v.y; p[2] = v.z; p[3] = v.w;
    }
    __syncthreads();
    if (tid < 240) {
        int g = tid / PB, p = tid - (tid / PB) * PB;
        float acc = 0.f;
        for (int d = g; d < DIM; d += 6) {
            float x = S[d * 41 + p];
            acc = fmaf(x, x, acc);
        }
        part[g * PB + p] = acc;
    }
    __syncthreads();
    if (tid < PB) {
        float s = 0.f;
        #pragma unroll
        for (int g = 0; g < 6; ++g) s += part[g * PB + tid];
        rn[tid] = 1.0f / fmaxf(sqrtf(s), 1e-12f);
    }
    __syncthreads();

    // 1280 jobs: (p, 8-wide d-group) -> two uint4 stores (hi, lo')
    _Float16* dst = isE ? XE : XT;
    #pragma unroll
    for (int i = 0; i < 5; ++i) {
        int idx = tid + i * 256;
        int p = idx >> 5, dg = idx & 31;
        int d0 = dg * 8;
        float r = rn[p];
        union { _Float16 f[8]; uint4 u; } hv, lv;
        #pragma unroll
        for (int j = 0; j < 8; ++j) {
            float x = S[(d0 + j) * 41 + p] * r;
            _Float16 h = (_Float16)x;
            hv.f[j] = h;
            lv.f[j] = (_Float16)((x - (float)h) * 4096.0f);
        }
        int kc = dg >> 2, dd = (dg & 3) * 8;
        size_t base = (size_t)(k * PB + p) * ROWH;
        if (isE) {  // enroll: [lo' | hi]
            *(uint4*)(dst + base + kc * 40 + dd)       = lv.u;
            *(uint4*)(dst + base + (8 + kc) * 40 + dd) = hv.u;
        } else {    // test:   [hi | lo']
            *(uint4*)(dst + base + kc * 40 + dd)       = hv.u;
            *(uint4*)(dst + base + (8 + kc) * 40 + dd) = lv.u;
        }
    }
}

// ---------------- Kernel 2: fully fused GEMM + gate1 + j-sum + gate2 + i-sum -> out[K,K] ----------------
struct Jobs {
    const char* gA[4]; int lA[4]; bool aA[4];
    const char* gB[3]; int lB[3]; bool aB[3];
};

__device__ __forceinline__ void issue(const Jobs& J, int it, int buf, void* LAp, void* LBp) {
    int kA = (it < 16) ? it : it - 16;        // A: full [hi|lo'] pass, then hi chunks 0..7
    int kB = (it < 16) ? it : it - 8;         // B: full [lo'|hi] pass, then hi chunks 8..15
    char* la = (char*)LAp + buf * SZA;
    char* lb = (char*)LBp + buf * SZB;
    #pragma unroll
    for (int j = 0; j < 4; ++j) if (J.aA[j]) CP16(J.gA[j] + kA * 80, la + J.lA[j]);
    #pragma unroll
    for (int j = 0; j < 3; ++j) if (J.aB[j]) CP16(J.gB[j] + kB * 80, lb + J.lB[j]);
}

__global__ __launch_bounds__(256, 3) void k_gemm(const _Float16* __restrict__ XT,
                                                 const _Float16* __restrict__ XE,
                                                 const float2* __restrict__ gtab,
                                                 const float* __restrict__ fc1_w,
                                                 const float* __restrict__ fc1_b,
                                                 const float* __restrict__ fc2_w,
                                                 float* __restrict__ out) {
    __shared__ __align__(16) _Float16 LA[2][BM * LDA];    // 25600 B
    __shared__ __align__(16) _Float16 LB[2][BNS * LDA];   // 20480 B
    __shared__ float ph2[4][132];                         // block-local pho2 [lgroup][col]

    int tid = threadIdx.x, lane = tid & 63, wv = tid >> 6;
    int m0 = blockIdx.y * BM;
    int n0 = blockIdx.x * BNV;                            // steps of 120; stages 128 (8 masked)

    // per-thread staging jobs (lane-linear LDS: required by global_load_lds)
    Jobs J;
    #pragma unroll
    for (int j = 0; j < 4; ++j) {
        int idx = tid + j * 256;
        J.aA[j] = idx < BM * 5;                           // 800 chunks
        int row = idx / 5, c5 = idx - row * 5;
        J.gA[j] = (const char*)XT + (size_t)(m0 + (J.aA[j] ? row : 0)) * (ROWH * 2) + c5 * 16;
        J.lA[j] = idx * 16;
    }
    #pragma unroll
    for (int j = 0; j < 3; ++j) {
        int idx = tid + j * 256;
        J.aB[j] = idx < BNS * 5;                          // 640 chunks
        int row = idx / 5, c5 = idx - row * 5;
        int gr = n0 + row; if (gr > MDIM - 1) gr = MDIM - 1;   // clamp tail block overread
        J.gB[j] = (const char*)XE + (size_t)(J.aB[j] ? gr : 0) * (ROWH * 2) + c5 * 16;
        J.lB[j] = idx * 16;
    }

    int wm = (wv & 1) * 80;
    int wn = (wv >> 1) * 64;
    int r15 = lane & 15, q4 = lane >> 4;

    int aoff[5], boff[4];
    #pragma unroll
    for (int mt = 0; mt < 5; ++mt) aoff[mt] = (wm + mt * 16 + r15) * LDA + q4 * 8;
    #pragma unroll
    for (int nt = 0; nt < 4; ++nt) boff[nt] = (wn + nt * 16 + r15) * LDA + q4 * 8;

    v4f acc[5][4];
    #pragma unroll
    for (int mt = 0; mt < 5; ++mt)
        #pragma unroll
        for (int nt = 0; nt < 4; ++nt)
            acc[mt][nt] = (v4f)0.f;

    issue(J, 0, 0, LA, LB);
    for (int it = 0; it < 24; ++it) {
        int buf = it & 1;
        __syncthreads();                      // drains vmcnt -> loads(it) landed; frag reads of it-1 done
        if (it < 23) issue(J, it + 1, buf ^ 1, LA, LB);   // prefetch flies during MFMA below

        if (it == 16) {                       // cross terms done: scale by 2^-12 (exact)
            #pragma unroll
            for (int mt = 0; mt < 5; ++mt)
                #pragma unroll
                for (int nt = 0; nt < 4; ++nt)
                    acc[mt][nt] *= 0.000244140625f;
        }

        const _Float16* A = LA[buf];
        const _Float16* B = LB[buf];
        v8h af[5], bf[4];
        #pragma unroll
        for (int mt = 0; mt < 5; ++mt) af[mt] = *(const v8h*)(A + aoff[mt]);
        #pragma unroll
        for (int nt = 0; nt < 4; ++nt) bf[nt] = *(const v8h*)(B + boff[nt]);
        #pragma unroll
        for (int mt = 0; mt < 5; ++mt)
            #pragma unroll
            for (int nt = 0; nt < 4; ++nt)
                acc[mt][nt] = __builtin_amdgcn_mfma_f32_16x16x32_f16(af[mt], bf[nt], acc[mt][nt], 0, 0, 0);
    }

    // ---- phase 1: gate1 (global table) + j-sum within wave -> ph2[lgroup][col] ----
    const float inv40 = 1.0f / (40.0f + 1e-6f);
    int lgb = wm / 40;                         // 0 or 2 (block-local l-group base)
    #pragma unroll
    for (int nt = 0; nt < 4; ++nt) {
        float s0 = 0.f, s1 = 0.f, t2 = 0.f;
        #pragma unroll
        for (int mt = 0; mt < 5; ++mt) {
            #pragma unroll
            for (int r = 0; r < 4; ++r) {
                float x = acc[mt][nt][r];
                float u = fmaf(x, 1024.0f, 1056.0f);
                int i = (int)u;
                i = min(max(i, 0), NTAB - 2);
                float f = u - (float)i;
                float2 tv = gtab[i];
                float xg = fmaf(f, tv.y, tv.x) * x;
                if (mt < 2)       s0 += xg;    // rows wm+0..31  -> group lgb
                else if (mt == 2) t2 += xg;    // rows wm+32..47 -> straddle on q4
                else              s1 += xg;    // rows wm+48..79 -> group lgb+1
            }
        }
        bool lo = (q4 < 2);
        s0 += lo ? t2 : 0.f;
        s1 += lo ? 0.f : t2;
        s0 += __shfl_xor(s0, 16); s0 += __shfl_xor(s0, 32);
        s1 += __shfl_xor(s1, 16); s1 += __shfl_xor(s1, 32);
        if (q4 == 0) {
            int col = wn + nt * 16 + r15;
            ph2[lgb][col]     = s0 * inv40;
            ph2[lgb + 1][col] = s1 * inv40;
        }
    }
    __syncthreads();

    // ---- phase 2: gate2 (tanhf, range-safe) + i-sum -> 12 final outputs ----
    float w2[CH], b2[CH], v2[CH];
    #pragma unroll
    for (int c = 0; c < CH; ++c) { w2[c] = fc1_w[c]; b2[c] = fc1_b[c]; v2[c] = fc2_w[c]; }

    #pragma unroll
    for (int r = 0; r < 3; ++r) {              // k-group r, l-group wv
        float x = (lane < PB) ? ph2[wv][r * PB + lane] : 0.f;
        float s = gate_ref(x, w2, b2, v2) * x;
        #pragma unroll
        for (int off = 32; off; off >>= 1) s += __shfl_xor(s, off);
        if (lane == 0)
            out[(size_t)(blockIdx.x * 3 + r) * KTR + blockIdx.y * 4 + wv] = s * inv40;
    }
}

extern "C" void kernel_launch(void* const* d_in, const int* in_sizes, int n_in,
                              void* d_out, int out_size, void* d_ws, size_t ws_size,
                              hipStream_t stream) {
    const float* enroll = (const float*)d_in[0];
    const float* test   = (const float*)d_in[1];
    const float* fc1_w  = (const float*)d_in[2];
    const float* fc1_b  = (const float*)d_in[3];
    const float* fc2_w  = (const float*)d_in[4];
    float* out = (float*)d_out;

    _Float16* XT = (_Float16*)d_ws;                    // [3840][640] f16 (test:  hi|lo', padded rows)
    _Float16* XE = XT + (size_t)MDIM * ROWH;           // [3840][640] f16 (enroll: lo'|hi, padded rows)
    float2* gtabG = (float2*)(XE + (size_t)MDIM * ROWH);

    k_norm<<<2 * KTR + 9, 256, 0, stream>>>(enroll, test, fc1_w, fc1_b, fc2_w, XT, XE, gtabG);
    dim3 g2(MDIM / BNV, MDIM / BM);                    // (32, 24) = 768 blocks = 3/CU exactly
    k_gemm<<<g2, 256, 0, stream>>>(XT, XE, gtabG, fc1_w, fc1_b, fc2_w, out);
}